// Round 1
// baseline (25.004 us; speedup 1.0000x reference)
//
#include <hip/hip_runtime.h>
#include <hip/hip_bf16.h>

#define BATCH 64
#define DIM 64
#define BANKN 131072

typedef __bf16 bf16x8 __attribute__((ext_vector_type(8)));
typedef float f32x16 __attribute__((ext_vector_type(16)));

__device__ inline bf16x8 pack_bf16x8(float4 a, float4 b) {
  bf16x8 r;
  r[0] = (__bf16)a.x; r[1] = (__bf16)a.y; r[2] = (__bf16)a.z; r[3] = (__bf16)a.w;
  r[4] = (__bf16)b.x; r[5] = (__bf16)b.y; r[6] = (__bf16)b.z; r[7] = (__bf16)b.w;
  return r;
}

// One wave computes a 64(m) x 32(n) output tile:
//   C = E[64x64] * bank^T[64 x 131072] via 2 m-tiles x 4 k-steps of
//   v_mfma_f32_32x32x16_bf16, then dist = sqrt(||e||^2 + ||b||^2 - 2C).
__global__ __launch_bounds__(256) void mb_dist(const float* __restrict__ emb,
                                               const float* __restrict__ bank,
                                               float* __restrict__ out) {
  __shared__ float qn_lds[BATCH];

  const int tid  = threadIdx.x;
  const int lane = tid & 63;
  const int wave = tid >> 6;
  const int lr   = lane & 31;   // row-in-tile (A) / col (B,C)
  const int lh   = lane >> 5;   // k-group half

  // ---- qn[m] = ||e_m||^2 (exact fp32) into LDS; threads 0..63 ----
  if (tid < BATCH) {
    const float4* er = (const float4*)(emb + tid * DIM);
    float s = 0.f;
#pragma unroll
    for (int i = 0; i < DIM / 4; ++i) {
      float4 v = er[i];
      s = fmaf(v.x, v.x, s); s = fmaf(v.y, v.y, s);
      s = fmaf(v.z, v.z, s); s = fmaf(v.w, v.w, s);
    }
    qn_lds[tid] = s;
  }

  // ---- A fragments from emb (L1-hot, 16 KB shared by all waves) ----
  // a[mt][ks][j] = E[mt*32 + lr][ks*16 + lh*8 + j]
  bf16x8 a0[4], a1[4];
#pragma unroll
  for (int ks = 0; ks < 4; ++ks) {
    const float* r0 = emb + (0 * 32 + lr) * DIM + ks * 16 + lh * 8;
    const float* r1 = emb + (1 * 32 + lr) * DIM + ks * 16 + lh * 8;
    float4 u0 = ((const float4*)r0)[0];
    float4 u1 = ((const float4*)r0)[1];
    float4 w0 = ((const float4*)r1)[0];
    float4 w1 = ((const float4*)r1)[1];
    a0[ks] = pack_bf16x8(u0, u1);
    a1[ks] = pack_bf16x8(w0, w1);
  }

  // ---- B fragments from bank + ||b||^2 partial (exact fp32) ----
  // b[ks][j] = bank[n0 + lr][ks*16 + lh*8 + j]
  const int n0 = (blockIdx.x * 4 + wave) * 32;
  const float* brow = bank + (size_t)(n0 + lr) * DIM;
  float bsum = 0.f;
  bf16x8 bfr[4];
#pragma unroll
  for (int ks = 0; ks < 4; ++ks) {
    const float* p = brow + ks * 16 + lh * 8;
    float4 v0 = ((const float4*)p)[0];
    float4 v1 = ((const float4*)p)[1];
    bsum = fmaf(v0.x, v0.x, bsum); bsum = fmaf(v0.y, v0.y, bsum);
    bsum = fmaf(v0.z, v0.z, bsum); bsum = fmaf(v0.w, v0.w, bsum);
    bsum = fmaf(v1.x, v1.x, bsum); bsum = fmaf(v1.y, v1.y, bsum);
    bsum = fmaf(v1.z, v1.z, bsum); bsum = fmaf(v1.w, v1.w, bsum);
    bfr[ks] = pack_bf16x8(v0, v1);
  }
  // partner lane (lh^1) holds the other 32 elements of this row
  float bn = bsum + __shfl_xor(bsum, 32);

  // ---- MFMA: acc[mt] over 4 k-steps ----
  f32x16 acc0, acc1;
#pragma unroll
  for (int i = 0; i < 16; ++i) { acc0[i] = 0.f; acc1[i] = 0.f; }
#pragma unroll
  for (int ks = 0; ks < 4; ++ks) {
    acc0 = __builtin_amdgcn_mfma_f32_32x32x16_bf16(a0[ks], bfr[ks], acc0, 0, 0, 0);
    acc1 = __builtin_amdgcn_mfma_f32_32x32x16_bf16(a1[ks], bfr[ks], acc1, 0, 0, 0);
  }

  __syncthreads();  // qn_lds ready

  // ---- epilogue: C/D layout col = lane&31, row = (reg&3)+8*(reg>>2)+4*lh ----
  const int ncol = n0 + lr;
#pragma unroll
  for (int reg = 0; reg < 16; ++reg) {
    const int rr = (reg & 3) + 8 * (reg >> 2) + 4 * lh;
    {
      float d2 = fmaf(-2.f, acc0[reg], qn_lds[rr] + bn);
      out[(size_t)rr * BANKN + ncol] = sqrtf(fmaxf(d2, 0.f));
    }
    {
      float d2 = fmaf(-2.f, acc1[reg], qn_lds[32 + rr] + bn);
      out[(size_t)(32 + rr) * BANKN + ncol] = sqrtf(fmaxf(d2, 0.f));
    }
  }
}

extern "C" void kernel_launch(void* const* d_in, const int* in_sizes, int n_in,
                              void* d_out, int out_size, void* d_ws, size_t ws_size,
                              hipStream_t stream) {
  const float* emb  = (const float*)d_in[0];
  const float* bank = (const float*)d_in[1];
  float* out = (float*)d_out;
  // 1024 blocks x 256 threads; each block covers 4 waves x 32 bank rows = 128 rows
  mb_dist<<<dim3(BANKN / 128), dim3(256), 0, stream>>>(emb, bank, out);
}